// Round 7
// baseline (226.356 us; speedup 1.0000x reference)
//
#include <hip/hip_runtime.h>
#include <stdint.h>

#define D_    512
#define H_    2
#define HD_   256
#define B_    16
#define S_    1194
#define MTOK  19104          // B_*S_
#define MPAD  19200          // 150*128
#define SPAD  1216           // 19*64 = 38*32
#define NQKV  1536
#define NKT   38             // kv tiles of 32 (attn)
#define LOG2E 1.44269504088896340736f

typedef unsigned short u16;
typedef __attribute__((ext_vector_type(8))) short bf16x8;   // 8 bf16 = 4 VGPR
typedef __attribute__((ext_vector_type(4))) float f32x4;

__device__ inline u16 f2bf(float x) {
  union { float f; unsigned u; } c; c.f = x;
  unsigned r = c.u + 0x7fffu + ((c.u >> 16) & 1u);  // RNE
  return (u16)(r >> 16);
}

// async global->LDS, 16B per lane. LDS dest is wave-uniform base (HW adds
// lane*16); global src per-lane. All call sites use CONTIGUOUS src:
// lane l reads base + l*16 -> one instruction = 1KB sequential = 8 full lines.
__device__ inline void async_copy16(void* lds, const void* g) {
  __builtin_amdgcn_global_load_lds(
      (__attribute__((address_space(1))) void*)(g),
      (__attribute__((address_space(3))) void*)(lds),
      16, 0, 0);
}

// ---------------------------------------------------------------------------
// Kernel 1 (unchanged): X/W -> frag-major bf16.
// ---------------------------------------------------------------------------
__global__ void convert_kernel(const float* __restrict__ X,
                               const float* __restrict__ Wqkv,
                               const float* __restrict__ Wout,
                               u16* __restrict__ Xf,
                               u16* __restrict__ Wqf,
                               u16* __restrict__ Wof) {
  const int NXG = MPAD * 64;
  const int NQG = 12 * 8 * 16 * 64;
  const int NOG = 4 * 8 * 16 * 64;
  const int TOT = NXG + NQG + NOG;
  int stride = gridDim.x * blockDim.x;
  for (int g = blockIdx.x * blockDim.x + threadIdx.x; g < TOT; g += stride) {
    if (g < NXG) {
      int lane = g & 63, f = (g >> 6) & 15, kt = (g >> 10) & 7, mt = g >> 13;
      int i = mt * 128 + (f & 7) * 16 + (lane & 15);
      int k = kt * 64 + (f >> 3) * 32 + (lane >> 4) * 8;
      bf16x8 o;
      if (i < MTOK) {
        f32x4 v0 = *(const f32x4*)&X[(size_t)i * 512 + k];
        f32x4 v1 = *(const f32x4*)&X[(size_t)i * 512 + k + 4];
#pragma unroll
        for (int e = 0; e < 4; ++e) { o[e] = (short)f2bf(v0[e]); o[4 + e] = (short)f2bf(v1[e]); }
      } else {
#pragma unroll
        for (int e = 0; e < 8; ++e) o[e] = 0;
      }
      *(bf16x8*)&Xf[(size_t)g * 8] = o;
    } else if (g < NXG + NQG) {
      int gg = g - NXG;
      int lane = gg & 63, f = (gg >> 6) & 15, kt = (gg >> 10) & 7, nt = gg >> 13;
      int j = nt * 128 + (f & 7) * 16 + (lane & 15);
      int k = kt * 64 + (f >> 3) * 32 + (lane >> 4) * 8;
      bf16x8 o;
#pragma unroll
      for (int e = 0; e < 8; ++e) o[e] = (short)f2bf(Wqkv[(size_t)(k + e) * NQKV + j]);
      *(bf16x8*)&Wqf[(size_t)gg * 8] = o;
    } else {
      int gg = g - NXG - NQG;
      int lane = gg & 63, f = (gg >> 6) & 15, kt = (gg >> 10) & 7, nt = gg >> 13;
      int j = nt * 128 + (f & 7) * 16 + (lane & 15);
      int k = kt * 64 + (f >> 3) * 32 + (lane >> 4) * 8;
      bf16x8 o;
#pragma unroll
      for (int e = 0; e < 8; ++e) o[e] = (short)f2bf(Wout[(size_t)(k + e) * 512 + j]);
      *(bf16x8*)&Wof[(size_t)gg * 8] = o;
    }
  }
}

// ---------------------------------------------------------------------------
// Pipelined GEMM (unchanged from round 6).
// ---------------------------------------------------------------------------
template<int MODE>
__global__ __launch_bounds__(256, 2) void gemm_kernel(
    const u16* __restrict__ Af, const u16* __restrict__ Bf,
    const float* __restrict__ bias, int nb,
    u16* __restrict__ Qb, u16* __restrict__ Kf, u16* __restrict__ Vf,
    float* __restrict__ Cout)
{
  __shared__ u16 ldsA[2][16 * 512];
  __shared__ u16 ldsB[2][16 * 512];

  const int t  = threadIdx.x;
  const int l  = t & 63;
  const int w  = t >> 6;
  const int lr = l >> 4, lc = l & 15;

  const int nwg = gridDim.x;
  const int qq = nwg >> 3, rr8 = nwg & 7;
  const int xcd = blockIdx.x & 7, off = blockIdx.x >> 3;
  const int wgid = (xcd < rr8 ? xcd * (qq + 1) : rr8 * (qq + 1) + (xcd - rr8) * qq) + off;
  const int m0 = (wgid / nb) * 128;
  const int n0 = (wgid % nb) * 128;

  const u16* pA = Af + ((size_t)(m0 >> 7) * 128 + w) * 512 + l * 8;
  const u16* pB = Bf + ((size_t)(n0 >> 7) * 128 + w) * 512 + l * 8;

  f32x4 acc[4][4] = {};

#pragma unroll
  for (int c = 0; c < 4; ++c) {
    async_copy16(&ldsA[0][(c * 4 + w) * 512], pA + c * 2048);
    async_copy16(&ldsB[0][(c * 4 + w) * 512], pB + c * 2048);
  }
  __syncthreads();

  for (int kt = 0; kt < 8; ++kt) {
    const int cur = kt & 1;
    if (kt < 7) {
      const u16* qA = pA + (kt + 1) * 8192;
      const u16* qB = pB + (kt + 1) * 8192;
#pragma unroll
      for (int c = 0; c < 4; ++c) {
        async_copy16(&ldsA[cur ^ 1][(c * 4 + w) * 512], qA + c * 2048);
        async_copy16(&ldsB[cur ^ 1][(c * 4 + w) * 512], qB + c * 2048);
      }
    }
#pragma unroll
    for (int kk = 0; kk < 2; ++kk) {
      bf16x8 af[4], bfr[4];
#pragma unroll
      for (int m = 0; m < 4; ++m)
        af[m] = *(bf16x8*)&ldsA[cur][((kk * 8 + (w >> 1) * 4 + m) * 64 + l) * 8];
#pragma unroll
      for (int n = 0; n < 4; ++n)
        bfr[n] = *(bf16x8*)&ldsB[cur][((kk * 8 + (w & 1) * 4 + n) * 64 + l) * 8];
      __builtin_amdgcn_s_setprio(1);
#pragma unroll
      for (int m = 0; m < 4; ++m)
#pragma unroll
        for (int n = 0; n < 4; ++n)
          acc[m][n] = __builtin_amdgcn_mfma_f32_16x16x32_bf16(af[m], bfr[n], acc[m][n], 0, 0, 0);
      __builtin_amdgcn_s_setprio(0);
    }
    __syncthreads();
  }

  int jv[4]; float bj[4];
#pragma unroll
  for (int n = 0; n < 4; ++n) { jv[n] = n0 + (w & 1) * 64 + n * 16 + lc; bj[n] = bias[jv[n]]; }

#pragma unroll
  for (int m = 0; m < 4; ++m) {
#pragma unroll
    for (int r = 0; r < 4; ++r) {
      int i = m0 + (w >> 1) * 64 + m * 16 + lr * 4 + r;
      if (i >= MTOK) continue;
      if (MODE == 0) {
        int b = i / S_, s = i - b * S_;
        int stK  = s >> 5;
        int nfs  = (s >> 4) & 1;
        int lisK = s & 15;
        int lvhi = (s >> 3) & 3;
        int es   = s & 7;
#pragma unroll
        for (int n = 0; n < 4; ++n) {
          int j = jv[n];
          int which = j >> 9, h = (j >> 8) & 1, d = j & 255;
          int bh = b * H_ + h;
          u16 v = f2bf(acc[m][n][r] + bj[n]);
          if (which == 0) {
            Qb[((size_t)(bh * SPAD + s)) * HD_ + d] = v;
          } else if (which == 1) {
            Kf[(((size_t)(bh * NKT + stK)) * 16 + (d >> 5) * 2 + nfs) * 512 +
               (((d >> 3) & 3) * 16 + lisK) * 8 + (d & 7)] = v;
          } else {
            Vf[(((size_t)(bh * NKT + stK)) * 16 + (d >> 4)) * 512 +
               (lvhi * 16 + (d & 15)) * 8 + es] = v;
          }
        }
      } else {
#pragma unroll
        for (int n = 0; n < 4; ++n)
          Cout[(size_t)i * D_ + jv[n]] = acc[m][n][r] + bj[n];
      }
    }
  }
}

// ---------------------------------------------------------------------------
// Kernel 3: causal flash attention v4.
// 4 waves x 32 q-rows (QBLK=128): 2 row-groups share every K/V frag read ->
// 64 MFMA per wave per iter against the same 16 stage loads + 1 barrier.
// KVBLK=32 DOUBLE-BUFFERED (round-6 schedule). LDS 73 KB -> 2 blocks/CU.
// Grid 320 = 32 bh x 10 q-tiles, XCD-pinned, long blocks first.
// ---------------------------------------------------------------------------
__global__ __launch_bounds__(256, 2) void attn_kernel(
    const u16* __restrict__ Qb, const u16* __restrict__ Kf,
    const u16* __restrict__ Vf, u16* __restrict__ Obf)
{
  __shared__ u16 ldsK[2][16 * 512];     // 2 x 16 KiB, frag = kb*2+nf
  __shared__ u16 ldsV[2][16 * 512];     // 2 x 16 KiB, frag = d-block
  __shared__ u16 ldsP[4][32 * 36];      // per-wave P [32 q][32 kv], pad 36

  const int id   = blockIdx.x;          // 0..319
  const int xcd  = id & 7;
  const int slot = id >> 3;             // 0..39
  const int bh   = xcd + 8 * (slot / 10);
  const int qt   = 9 - (slot % 10);     // long blocks first
  const int q0   = qt * 128;
  const int nkv  = min(4 * qt + 4, NKT);
  const int t  = threadIdx.x, l = t & 63, w = t >> 6;
  const int lr = l >> 4, lc = l & 15;
  const int wq0 = q0 + w * 32;          // wave's first q row

  // Q fragments: 2 row-groups x 8 d-blocks (rows >= S_ clamp; discarded)
  bf16x8 qf[2][8];
#pragma unroll
  for (int a = 0; a < 2; ++a) {
    int qr = wq0 + a * 16 + lc; if (qr >= S_) qr = S_ - 1;
    const u16* qbase = Qb + (size_t)(bh * SPAD + qr) * HD_ + lr * 8;
#pragma unroll
    for (int kb = 0; kb < 8; ++kb)
      qf[a][kb] = *(const bf16x8*)(qbase + kb * 32);
  }

  f32x4 oacc[2][16] = {};
  float mrow[2][4], lsum[2][4];
#pragma unroll
  for (int a = 0; a < 2; ++a)
#pragma unroll
    for (int r = 0; r < 4; ++r) { mrow[a][r] = -1e30f; lsum[a][r] = 0.f; }

  // prologue: stage tile 0 into buf 0
  {
    const u16* kb_ = Kf + (((size_t)(bh * NKT)) * 16 + w) * 512 + l * 8;
    const u16* vb_ = Vf + (((size_t)(bh * NKT)) * 16 + w) * 512 + l * 8;
#pragma unroll
    for (int c = 0; c < 4; ++c) {
      async_copy16(&ldsK[0][(c * 4 + w) * 512], kb_ + c * 2048);
      async_copy16(&ldsV[0][(c * 4 + w) * 512], vb_ + c * 2048);
    }
  }
  __syncthreads();

  for (int kt = 0; kt < nkv; ++kt) {
    const int cur = kt & 1;
    if (kt + 1 < nkv) {                 // issue next tile's stages FIRST
      const u16* kb_ = Kf + (((size_t)(bh * NKT + kt + 1)) * 16 + w) * 512 + l * 8;
      const u16* vb_ = Vf + (((size_t)(bh * NKT + kt + 1)) * 16 + w) * 512 + l * 8;
#pragma unroll
      for (int c = 0; c < 4; ++c) {
        async_copy16(&ldsK[cur ^ 1][(c * 4 + w) * 512], kb_ + c * 2048);
        async_copy16(&ldsV[cur ^ 1][(c * 4 + w) * 512], vb_ + c * 2048);
      }
    }

    // S = Q @ K^T  (2 x 16q x 32kv; each K frag read once)
    f32x4 sacc[2][2] = {};
    __builtin_amdgcn_s_setprio(1);
#pragma unroll
    for (int kb = 0; kb < 8; ++kb) {
#pragma unroll
      for (int nf = 0; nf < 2; ++nf) {
        bf16x8 kf = *(bf16x8*)&ldsK[cur][((kb * 2 + nf) * 64 + l) * 8];
        sacc[0][nf] = __builtin_amdgcn_mfma_f32_16x16x32_bf16(qf[0][kb], kf, sacc[0][nf], 0, 0, 0);
        sacc[1][nf] = __builtin_amdgcn_mfma_f32_16x16x32_bf16(qf[1][kb], kf, sacc[1][nf], 0, 0, 0);
      }
    }
    __builtin_amdgcn_s_setprio(0);

    const int kv0 = kt * 32;
    float pm[2][4];
    float sval[2][2][4];
#pragma unroll
    for (int a = 0; a < 2; ++a) {
#pragma unroll
      for (int r = 0; r < 4; ++r) pm[a][r] = -1e30f;
      if (kv0 + 31 <= wq0 + a * 16) {   // interior for this row-group
#pragma unroll
        for (int nf = 0; nf < 2; ++nf)
#pragma unroll
          for (int r = 0; r < 4; ++r) {
            float v = sacc[a][nf][r] * 0.0625f;
            sval[a][nf][r] = v;
            pm[a][r] = fmaxf(pm[a][r], v);
          }
      } else {
#pragma unroll
        for (int nf = 0; nf < 2; ++nf) {
          int col = kv0 + nf * 16 + lc;
#pragma unroll
          for (int r = 0; r < 4; ++r) {
            int row = wq0 + a * 16 + lr * 4 + r;
            float v = ((col <= row) && (col < S_)) ? sacc[a][nf][r] * 0.0625f : -1e30f;
            sval[a][nf][r] = v;
            pm[a][r] = fmaxf(pm[a][r], v);
          }
        }
      }
#pragma unroll
      for (int r = 0; r < 4; ++r) {
        pm[a][r] = fmaxf(pm[a][r], __shfl_xor(pm[a][r], 1));
        pm[a][r] = fmaxf(pm[a][r], __shfl_xor(pm[a][r], 2));
        pm[a][r] = fmaxf(pm[a][r], __shfl_xor(pm[a][r], 4));
        pm[a][r] = fmaxf(pm[a][r], __shfl_xor(pm[a][r], 8));
      }
    }
    // defer-max (T13): one vote across both row-groups
    bool skip = true;
#pragma unroll
    for (int a = 0; a < 2; ++a)
#pragma unroll
      for (int r = 0; r < 4; ++r) skip = skip && (pm[a][r] <= mrow[a][r] + 8.0f);
    if (!__all(skip)) {
#pragma unroll
      for (int a = 0; a < 2; ++a)
#pragma unroll
        for (int r = 0; r < 4; ++r) {
          float mn = fmaxf(mrow[a][r], pm[a][r]);
          float sc = exp2f((mrow[a][r] - mn) * LOG2E);
          mrow[a][r] = mn;
          lsum[a][r] *= sc;
#pragma unroll
          for (int nf = 0; nf < 16; ++nf) oacc[a][nf][r] *= sc;
        }
    }
#pragma unroll
    for (int a = 0; a < 2; ++a)
#pragma unroll
      for (int nf = 0; nf < 2; ++nf)
#pragma unroll
        for (int r = 0; r < 4; ++r) {
          float p = exp2f((sval[a][nf][r] - mrow[a][r]) * LOG2E);
          lsum[a][r] += p;
          ldsP[w][(a * 16 + lr * 4 + r) * 36 + nf * 16 + lc] = f2bf(p);
        }
    // no barrier: P is wave-private (same-wave lgkm ordering)

    // O += P @ V  (each V frag read once, used by both row-groups)
    bf16x8 pf0 = *(bf16x8*)&ldsP[w][lc * 36 + lr * 8];
    bf16x8 pf1 = *(bf16x8*)&ldsP[w][(16 + lc) * 36 + lr * 8];
    __builtin_amdgcn_s_setprio(1);
#pragma unroll
    for (int nf = 0; nf < 16; ++nf) {
      bf16x8 vf = *(bf16x8*)&ldsV[cur][(nf * 64 + l) * 8];
      oacc[0][nf] = __builtin_amdgcn_mfma_f32_16x16x32_bf16(pf0, vf, oacc[0][nf], 0, 0, 0);
      oacc[1][nf] = __builtin_amdgcn_mfma_f32_16x16x32_bf16(pf1, vf, oacc[1][nf], 0, 0, 0);
    }
    __builtin_amdgcn_s_setprio(0);
    __syncthreads();                    // all waves done with cur; nxt landed
  }

  // finalize + write Obf (frag-major A-layout for out-proj GEMM)
  const int b = bh >> 1, h = bh & 1;
#pragma unroll
  for (int a = 0; a < 2; ++a) {
    float inv[4];
#pragma unroll
    for (int r = 0; r < 4; ++r) {
      float s = lsum[a][r];
      s += __shfl_xor(s, 1); s += __shfl_xor(s, 2);
      s += __shfl_xor(s, 4); s += __shfl_xor(s, 8);
      inv[r] = 1.0f / s;
    }
#pragma unroll
    for (int r = 0; r < 4; ++r) {
      int qrow = wq0 + a * 16 + lr * 4 + r;
      if (qrow < S_) {
        int i = b * S_ + qrow;
        int it = i >> 7, mf = (i >> 4) & 7, li = i & 15;
#pragma unroll
        for (int nf = 0; nf < 16; ++nf) {
          int j = h * HD_ + nf * 16 + lc;
          size_t addr = (((size_t)(it * 8 + (j >> 6))) * 16 + ((j >> 5) & 1) * 8 + mf) * 512 +
                        (((j >> 3) & 3) * 16 + li) * 8 + (j & 7);
          Obf[addr] = f2bf(oacc[a][nf][r] * inv[r]);
        }
      }
    }
  }
}

// ---------------------------------------------------------------------------
extern "C" void kernel_launch(void* const* d_in, const int* in_sizes, int n_in,
                              void* d_out, int out_size, void* d_ws, size_t ws_size,
                              hipStream_t stream) {
  const float* X    = (const float*)d_in[0];
  const float* Wqkv = (const float*)d_in[1];
  const float* bqkv = (const float*)d_in[2];
  const float* Wout = (const float*)d_in[3];
  const float* bout = (const float*)d_in[4];
  float* out = (float*)d_out;

  char* ws = (char*)d_ws;
  u16* Xf  = (u16*)ws;  ws += (size_t)MPAD * D_ * 2;
  u16* Wqf = (u16*)ws;  ws += (size_t)NQKV * D_ * 2;
  u16* Wof = (u16*)ws;  ws += (size_t)D_ * D_ * 2;
  u16* Qb  = (u16*)ws;  ws += (size_t)B_ * H_ * SPAD * HD_ * 2;
  u16* Kf  = (u16*)ws;  ws += (size_t)B_ * H_ * SPAD * HD_ * 2;
  u16* Vf  = (u16*)ws;  ws += (size_t)B_ * H_ * SPAD * HD_ * 2;
  u16* Obf = (u16*)ws;  ws += (size_t)MPAD * D_ * 2;
  // total ~101 MB

  convert_kernel<<<2048, 256, 0, stream>>>(X, Wqkv, Wout, Xf, Wqf, Wof);
  gemm_kernel<0><<<1800, 256, 0, stream>>>(Xf, Wqf, bqkv, 12, Qb, Kf, Vf, nullptr);
  attn_kernel<<<320, 256, 0, stream>>>(Qb, Kf, Vf, Obf);
  gemm_kernel<1><<<600, 256, 0, stream>>>(Obf, Wof, bout, 4, nullptr, nullptr, nullptr, out);
}

// Round 8
// 178.488 us; speedup vs baseline: 1.2682x; 1.2682x over previous
//
#include <hip/hip_runtime.h>
#include <stdint.h>

#define D_    512
#define H_    2
#define HD_   256
#define B_    16
#define S_    1194
#define MTOK  19104          // B_*S_
#define MPAD  19200          // 150*128
#define SPAD  1216           // 19*64 = 38*32
#define NQKV  1536
#define NKT   38             // kv tiles of 32 (attn)
#define LOG2E 1.44269504088896340736f

typedef unsigned short u16;
typedef __attribute__((ext_vector_type(8))) short bf16x8;   // 8 bf16 = 4 VGPR
typedef __attribute__((ext_vector_type(4))) float f32x4;

__device__ inline u16 f2bf(float x) {
  union { float f; unsigned u; } c; c.f = x;
  unsigned r = c.u + 0x7fffu + ((c.u >> 16) & 1u);  // RNE
  return (u16)(r >> 16);
}

// async global->LDS, 16B per lane. LDS dest is wave-uniform base (HW adds
// lane*16); global src per-lane. All call sites use CONTIGUOUS src:
// lane l reads base + l*16 -> one instruction = 1KB sequential = 8 full lines.
__device__ inline void async_copy16(void* lds, const void* g) {
  __builtin_amdgcn_global_load_lds(
      (__attribute__((address_space(1))) void*)(g),
      (__attribute__((address_space(3))) void*)(lds),
      16, 0, 0);
}

// ---------------------------------------------------------------------------
// Kernel 1 (unchanged): X/W -> frag-major bf16.
// ---------------------------------------------------------------------------
__global__ void convert_kernel(const float* __restrict__ X,
                               const float* __restrict__ Wqkv,
                               const float* __restrict__ Wout,
                               u16* __restrict__ Xf,
                               u16* __restrict__ Wqf,
                               u16* __restrict__ Wof) {
  const int NXG = MPAD * 64;
  const int NQG = 12 * 8 * 16 * 64;
  const int NOG = 4 * 8 * 16 * 64;
  const int TOT = NXG + NQG + NOG;
  int stride = gridDim.x * blockDim.x;
  for (int g = blockIdx.x * blockDim.x + threadIdx.x; g < TOT; g += stride) {
    if (g < NXG) {
      int lane = g & 63, f = (g >> 6) & 15, kt = (g >> 10) & 7, mt = g >> 13;
      int i = mt * 128 + (f & 7) * 16 + (lane & 15);
      int k = kt * 64 + (f >> 3) * 32 + (lane >> 4) * 8;
      bf16x8 o;
      if (i < MTOK) {
        f32x4 v0 = *(const f32x4*)&X[(size_t)i * 512 + k];
        f32x4 v1 = *(const f32x4*)&X[(size_t)i * 512 + k + 4];
#pragma unroll
        for (int e = 0; e < 4; ++e) { o[e] = (short)f2bf(v0[e]); o[4 + e] = (short)f2bf(v1[e]); }
      } else {
#pragma unroll
        for (int e = 0; e < 8; ++e) o[e] = 0;
      }
      *(bf16x8*)&Xf[(size_t)g * 8] = o;
    } else if (g < NXG + NQG) {
      int gg = g - NXG;
      int lane = gg & 63, f = (gg >> 6) & 15, kt = (gg >> 10) & 7, nt = gg >> 13;
      int j = nt * 128 + (f & 7) * 16 + (lane & 15);
      int k = kt * 64 + (f >> 3) * 32 + (lane >> 4) * 8;
      bf16x8 o;
#pragma unroll
      for (int e = 0; e < 8; ++e) o[e] = (short)f2bf(Wqkv[(size_t)(k + e) * NQKV + j]);
      *(bf16x8*)&Wqf[(size_t)gg * 8] = o;
    } else {
      int gg = g - NXG - NQG;
      int lane = gg & 63, f = (gg >> 6) & 15, kt = (gg >> 10) & 7, nt = gg >> 13;
      int j = nt * 128 + (f & 7) * 16 + (lane & 15);
      int k = kt * 64 + (f >> 3) * 32 + (lane >> 4) * 8;
      bf16x8 o;
#pragma unroll
      for (int e = 0; e < 8; ++e) o[e] = (short)f2bf(Wout[(size_t)(k + e) * 512 + j]);
      *(bf16x8*)&Wof[(size_t)gg * 8] = o;
    }
  }
}

// ---------------------------------------------------------------------------
// Pipelined GEMM (unchanged from round 6).
// ---------------------------------------------------------------------------
template<int MODE>
__global__ __launch_bounds__(256, 2) void gemm_kernel(
    const u16* __restrict__ Af, const u16* __restrict__ Bf,
    const float* __restrict__ bias, int nb,
    u16* __restrict__ Qb, u16* __restrict__ Kf, u16* __restrict__ Vf,
    float* __restrict__ Cout)
{
  __shared__ u16 ldsA[2][16 * 512];
  __shared__ u16 ldsB[2][16 * 512];

  const int t  = threadIdx.x;
  const int l  = t & 63;
  const int w  = t >> 6;
  const int lr = l >> 4, lc = l & 15;

  const int nwg = gridDim.x;
  const int qq = nwg >> 3, rr8 = nwg & 7;
  const int xcd = blockIdx.x & 7, off = blockIdx.x >> 3;
  const int wgid = (xcd < rr8 ? xcd * (qq + 1) : rr8 * (qq + 1) + (xcd - rr8) * qq) + off;
  const int m0 = (wgid / nb) * 128;
  const int n0 = (wgid % nb) * 128;

  const u16* pA = Af + ((size_t)(m0 >> 7) * 128 + w) * 512 + l * 8;
  const u16* pB = Bf + ((size_t)(n0 >> 7) * 128 + w) * 512 + l * 8;

  f32x4 acc[4][4] = {};

#pragma unroll
  for (int c = 0; c < 4; ++c) {
    async_copy16(&ldsA[0][(c * 4 + w) * 512], pA + c * 2048);
    async_copy16(&ldsB[0][(c * 4 + w) * 512], pB + c * 2048);
  }
  __syncthreads();

  for (int kt = 0; kt < 8; ++kt) {
    const int cur = kt & 1;
    if (kt < 7) {
      const u16* qA = pA + (kt + 1) * 8192;
      const u16* qB = pB + (kt + 1) * 8192;
#pragma unroll
      for (int c = 0; c < 4; ++c) {
        async_copy16(&ldsA[cur ^ 1][(c * 4 + w) * 512], qA + c * 2048);
        async_copy16(&ldsB[cur ^ 1][(c * 4 + w) * 512], qB + c * 2048);
      }
    }
#pragma unroll
    for (int kk = 0; kk < 2; ++kk) {
      bf16x8 af[4], bfr[4];
#pragma unroll
      for (int m = 0; m < 4; ++m)
        af[m] = *(bf16x8*)&ldsA[cur][((kk * 8 + (w >> 1) * 4 + m) * 64 + l) * 8];
#pragma unroll
      for (int n = 0; n < 4; ++n)
        bfr[n] = *(bf16x8*)&ldsB[cur][((kk * 8 + (w & 1) * 4 + n) * 64 + l) * 8];
      __builtin_amdgcn_s_setprio(1);
#pragma unroll
      for (int m = 0; m < 4; ++m)
#pragma unroll
        for (int n = 0; n < 4; ++n)
          acc[m][n] = __builtin_amdgcn_mfma_f32_16x16x32_bf16(af[m], bfr[n], acc[m][n], 0, 0, 0);
      __builtin_amdgcn_s_setprio(0);
    }
    __syncthreads();
  }

  int jv[4]; float bj[4];
#pragma unroll
  for (int n = 0; n < 4; ++n) { jv[n] = n0 + (w & 1) * 64 + n * 16 + lc; bj[n] = bias[jv[n]]; }

#pragma unroll
  for (int m = 0; m < 4; ++m) {
#pragma unroll
    for (int r = 0; r < 4; ++r) {
      int i = m0 + (w >> 1) * 64 + m * 16 + lr * 4 + r;
      if (i >= MTOK) continue;
      if (MODE == 0) {
        int b = i / S_, s = i - b * S_;
        int stK  = s >> 5;
        int nfs  = (s >> 4) & 1;
        int lisK = s & 15;
        int lvhi = (s >> 3) & 3;
        int es   = s & 7;
#pragma unroll
        for (int n = 0; n < 4; ++n) {
          int j = jv[n];
          int which = j >> 9, h = (j >> 8) & 1, d = j & 255;
          int bh = b * H_ + h;
          u16 v = f2bf(acc[m][n][r] + bj[n]);
          if (which == 0) {
            Qb[((size_t)(bh * SPAD + s)) * HD_ + d] = v;
          } else if (which == 1) {
            Kf[(((size_t)(bh * NKT + stK)) * 16 + (d >> 5) * 2 + nfs) * 512 +
               (((d >> 3) & 3) * 16 + lisK) * 8 + (d & 7)] = v;
          } else {
            Vf[(((size_t)(bh * NKT + stK)) * 16 + (d >> 4)) * 512 +
               (lvhi * 16 + (d & 15)) * 8 + es] = v;
          }
        }
      } else {
#pragma unroll
        for (int n = 0; n < 4; ++n)
          Cout[(size_t)i * D_ + jv[n]] = acc[m][n][r] + bj[n];
      }
    }
  }
}

// ---------------------------------------------------------------------------
// Kernel 3: causal flash attention v5 = round-6 structure (4 waves x 16 q,
// grid 608, KVBLK=32, K double-buffered in LDS) + V DIRECT-TO-REGISTERS:
// ldsV removed; each wave loads its 16 V-frags via global_load_dwordx4
// issued FIRST in the iteration (T14: latency hidden under QK^T + softmax;
// counted vmcnt leaves K-stages in flight). LDS reads/block-iter halve
// (128->64 KB); LDS 36.6 KB; staging volume halves.
// ---------------------------------------------------------------------------
__global__ __launch_bounds__(256, 2) void attn_kernel(
    const u16* __restrict__ Qb, const u16* __restrict__ Kf,
    const u16* __restrict__ Vf, u16* __restrict__ Obf)
{
  __shared__ u16 ldsK[2][16 * 512];     // 2 x 16 KiB, frag = kb*2+nf
  __shared__ u16 ldsP[4][16 * 36];      // per-wave P [16 q][32 kv], pad 36

  const int id   = blockIdx.x;          // 0..607
  const int xcd  = id & 7;
  const int slot = id >> 3;             // 0..75
  const int bh   = xcd + 8 * (slot / 19);
  const int qt   = 18 - (slot % 19);    // long blocks first
  const int q0   = qt * 64;
  const int nkv  = 2 * qt + 2;          // kv tiles of 32
  const int t  = threadIdx.x, l = t & 63, w = t >> 6;
  const int lr = l >> 4, lc = l & 15;
  const int wq0 = q0 + w * 16;          // wave's first q row

  // Q fragments: 8 d-blocks of 32
  bf16x8 qf[8];
  const u16* qbase = Qb + (size_t)(bh * SPAD + wq0 + lc) * HD_ + lr * 8;
#pragma unroll
  for (int kb = 0; kb < 8; ++kb)
    qf[kb] = *(const bf16x8*)(qbase + kb * 32);

  f32x4 oacc[16] = {};
  float mrow[4] = {-1e30f, -1e30f, -1e30f, -1e30f};
  float lsum[4] = {0.f, 0.f, 0.f, 0.f};

  // prologue: stage K tile 0 into buf 0 (V is loaded per-iter to registers)
  {
    const u16* kb_ = Kf + (((size_t)(bh * NKT)) * 16 + w) * 512 + l * 8;
#pragma unroll
    for (int c = 0; c < 4; ++c)
      async_copy16(&ldsK[0][(c * 4 + w) * 512], kb_ + c * 2048);
  }
  __syncthreads();

  for (int kt = 0; kt < nkv; ++kt) {
    const int cur = kt & 1;

    // (1) V-frag loads for CURRENT tile, issued first (consumed after softmax)
    bf16x8 vfr[16];
    {
      const u16* vb_ = Vf + (((size_t)(bh * NKT + kt)) * 16) * 512 + l * 8;
#pragma unroll
      for (int nf = 0; nf < 16; ++nf)
        vfr[nf] = *(const bf16x8*)(vb_ + nf * 512);
    }

    // (2) next K tile's stages (stay in flight across the compute)
    if (kt + 1 < nkv) {
      const u16* kb_ = Kf + (((size_t)(bh * NKT + kt + 1)) * 16 + w) * 512 + l * 8;
#pragma unroll
      for (int c = 0; c < 4; ++c)
        async_copy16(&ldsK[cur ^ 1][(c * 4 + w) * 512], kb_ + c * 2048);
    }

    // (3) S = Q @ K^T  (16q x 32kv)
    f32x4 sacc[2] = {};
    __builtin_amdgcn_s_setprio(1);
#pragma unroll
    for (int kb = 0; kb < 8; ++kb) {
#pragma unroll
      for (int nf = 0; nf < 2; ++nf) {
        bf16x8 kf = *(bf16x8*)&ldsK[cur][((kb * 2 + nf) * 64 + l) * 8];
        sacc[nf] = __builtin_amdgcn_mfma_f32_16x16x32_bf16(qf[kb], kf, sacc[nf], 0, 0, 0);
      }
    }
    __builtin_amdgcn_s_setprio(0);

    // (4) mask + online softmax (scale 1/16)
    const int kv0 = kt * 32;
    float sval[2][4];
    float pm[4] = {-1e30f, -1e30f, -1e30f, -1e30f};
    if (kv0 + 31 <= wq0) {              // interior tile: no masking needed
#pragma unroll
      for (int nf = 0; nf < 2; ++nf)
#pragma unroll
        for (int r = 0; r < 4; ++r) {
          float v = sacc[nf][r] * 0.0625f;
          sval[nf][r] = v;
          pm[r] = fmaxf(pm[r], v);
        }
    } else {
#pragma unroll
      for (int nf = 0; nf < 2; ++nf) {
        int col = kv0 + nf * 16 + lc;
#pragma unroll
        for (int r = 0; r < 4; ++r) {
          int row = wq0 + lr * 4 + r;
          float v = ((col <= row) && (col < S_)) ? sacc[nf][r] * 0.0625f : -1e30f;
          sval[nf][r] = v;
          pm[r] = fmaxf(pm[r], v);
        }
      }
    }
#pragma unroll
    for (int r = 0; r < 4; ++r) {
      pm[r] = fmaxf(pm[r], __shfl_xor(pm[r], 1));
      pm[r] = fmaxf(pm[r], __shfl_xor(pm[r], 2));
      pm[r] = fmaxf(pm[r], __shfl_xor(pm[r], 4));
      pm[r] = fmaxf(pm[r], __shfl_xor(pm[r], 8));
    }
    // defer-max (T13): skip rescale if max grew by <= 8 everywhere
    bool skip = (pm[0] <= mrow[0] + 8.0f) && (pm[1] <= mrow[1] + 8.0f) &&
                (pm[2] <= mrow[2] + 8.0f) && (pm[3] <= mrow[3] + 8.0f);
    if (!__all(skip)) {
#pragma unroll
      for (int r = 0; r < 4; ++r) {
        float mn = fmaxf(mrow[r], pm[r]);
        float sc = exp2f((mrow[r] - mn) * LOG2E);
        mrow[r] = mn;
        lsum[r] *= sc;
#pragma unroll
        for (int nf = 0; nf < 16; ++nf) oacc[nf][r] *= sc;
      }
    }
#pragma unroll
    for (int nf = 0; nf < 2; ++nf)
#pragma unroll
      for (int r = 0; r < 4; ++r) {
        float p = exp2f((sval[nf][r] - mrow[r]) * LOG2E);
        lsum[r] += p;
        ldsP[w][(lr * 4 + r) * 36 + nf * 16 + lc] = f2bf(p);
      }
    // no barrier: P is wave-private (same-wave lgkm ordering)

    // (5) O += P @ V  (one P A-frag, 16 V frags from REGISTERS)
    bf16x8 pf = *(bf16x8*)&ldsP[w][lc * 36 + lr * 8];
    __builtin_amdgcn_s_setprio(1);
#pragma unroll
    for (int nf = 0; nf < 16; ++nf)
      oacc[nf] = __builtin_amdgcn_mfma_f32_16x16x32_bf16(pf, vfr[nf], oacc[nf], 0, 0, 0);
    __builtin_amdgcn_s_setprio(0);
    __syncthreads();                    // all waves done with cur K; nxt landed
  }

  // finalize + write Obf (frag-major A-layout for out-proj GEMM)
  float inv[4];
#pragma unroll
  for (int r = 0; r < 4; ++r) {
    float s = lsum[r];
    s += __shfl_xor(s, 1); s += __shfl_xor(s, 2);
    s += __shfl_xor(s, 4); s += __shfl_xor(s, 8);
    inv[r] = 1.0f / s;
  }
  const int b = bh >> 1, h = bh & 1;
#pragma unroll
  for (int r = 0; r < 4; ++r) {
    int qrow = wq0 + lr * 4 + r;
    if (qrow < S_) {
      int i = b * S_ + qrow;
      int it = i >> 7, mf = (i >> 4) & 7, li = i & 15;
#pragma unroll
      for (int nf = 0; nf < 16; ++nf) {
        int j = h * HD_ + nf * 16 + lc;
        size_t addr = (((size_t)(it * 8 + (j >> 6))) * 16 + ((j >> 5) & 1) * 8 + mf) * 512 +
                      (((j >> 3) & 3) * 16 + li) * 8 + (j & 7);
        Obf[addr] = f2bf(oacc[nf][r] * inv[r]);
      }
    }
  }
}

// ---------------------------------------------------------------------------
extern "C" void kernel_launch(void* const* d_in, const int* in_sizes, int n_in,
                              void* d_out, int out_size, void* d_ws, size_t ws_size,
                              hipStream_t stream) {
  const float* X    = (const float*)d_in[0];
  const float* Wqkv = (const float*)d_in[1];
  const float* bqkv = (const float*)d_in[2];
  const float* Wout = (const float*)d_in[3];
  const float* bout = (const float*)d_in[4];
  float* out = (float*)d_out;

  char* ws = (char*)d_ws;
  u16* Xf  = (u16*)ws;  ws += (size_t)MPAD * D_ * 2;
  u16* Wqf = (u16*)ws;  ws += (size_t)NQKV * D_ * 2;
  u16* Wof = (u16*)ws;  ws += (size_t)D_ * D_ * 2;
  u16* Qb  = (u16*)ws;  ws += (size_t)B_ * H_ * SPAD * HD_ * 2;
  u16* Kf  = (u16*)ws;  ws += (size_t)B_ * H_ * SPAD * HD_ * 2;
  u16* Vf  = (u16*)ws;  ws += (size_t)B_ * H_ * SPAD * HD_ * 2;
  u16* Obf = (u16*)ws;  ws += (size_t)MPAD * D_ * 2;
  // total ~101 MB

  convert_kernel<<<2048, 256, 0, stream>>>(X, Wqkv, Wout, Xf, Wqf, Wof);
  gemm_kernel<0><<<1800, 256, 0, stream>>>(Xf, Wqf, bqkv, 12, Qb, Kf, Vf, nullptr);
  attn_kernel<<<608, 256, 0, stream>>>(Qb, Kf, Vf, Obf);
  gemm_kernel<1><<<600, 256, 0, stream>>>(Obf, Wof, bout, 4, nullptr, nullptr, nullptr, out);
}

// Round 9
// 165.931 us; speedup vs baseline: 1.3642x; 1.0757x over previous
//
#include <hip/hip_runtime.h>
#include <stdint.h>

#define D_    512
#define H_    2
#define HD_   256
#define B_    16
#define S_    1194
#define MTOK  19104          // B_*S_
#define MPAD  19200          // 150*128
#define SPAD  1216           // 19*64 = 38*32
#define NQKV  1536
#define NKT   38             // kv tiles of 32 (attn)
#define LOG2E 1.44269504088896340736f

typedef unsigned short u16;
typedef __attribute__((ext_vector_type(8))) short bf16x8;   // 8 bf16 = 4 VGPR
typedef __attribute__((ext_vector_type(4))) float f32x4;

__device__ inline u16 f2bf(float x) {
  union { float f; unsigned u; } c; c.f = x;
  unsigned r = c.u + 0x7fffu + ((c.u >> 16) & 1u);  // RNE
  return (u16)(r >> 16);
}

// async global->LDS, 16B per lane. LDS dest is wave-uniform base (HW adds
// lane*16); global src per-lane, CONTIGUOUS: 1 instr = 1KB sequential.
__device__ inline void async_copy16(void* lds, const void* g) {
  __builtin_amdgcn_global_load_lds(
      (__attribute__((address_space(1))) void*)(g),
      (__attribute__((address_space(3))) void*)(lds),
      16, 0, 0);
}

// ---------------------------------------------------------------------------
// Kernel 1 (unchanged): X/W -> frag-major bf16.
// ---------------------------------------------------------------------------
__global__ void convert_kernel(const float* __restrict__ X,
                               const float* __restrict__ Wqkv,
                               const float* __restrict__ Wout,
                               u16* __restrict__ Xf,
                               u16* __restrict__ Wqf,
                               u16* __restrict__ Wof) {
  const int NXG = MPAD * 64;
  const int NQG = 12 * 8 * 16 * 64;
  const int NOG = 4 * 8 * 16 * 64;
  const int TOT = NXG + NQG + NOG;
  int stride = gridDim.x * blockDim.x;
  for (int g = blockIdx.x * blockDim.x + threadIdx.x; g < TOT; g += stride) {
    if (g < NXG) {
      int lane = g & 63, f = (g >> 6) & 15, kt = (g >> 10) & 7, mt = g >> 13;
      int i = mt * 128 + (f & 7) * 16 + (lane & 15);
      int k = kt * 64 + (f >> 3) * 32 + (lane >> 4) * 8;
      bf16x8 o;
      if (i < MTOK) {
        f32x4 v0 = *(const f32x4*)&X[(size_t)i * 512 + k];
        f32x4 v1 = *(const f32x4*)&X[(size_t)i * 512 + k + 4];
#pragma unroll
        for (int e = 0; e < 4; ++e) { o[e] = (short)f2bf(v0[e]); o[4 + e] = (short)f2bf(v1[e]); }
      } else {
#pragma unroll
        for (int e = 0; e < 8; ++e) o[e] = 0;
      }
      *(bf16x8*)&Xf[(size_t)g * 8] = o;
    } else if (g < NXG + NQG) {
      int gg = g - NXG;
      int lane = gg & 63, f = (gg >> 6) & 15, kt = (gg >> 10) & 7, nt = gg >> 13;
      int j = nt * 128 + (f & 7) * 16 + (lane & 15);
      int k = kt * 64 + (f >> 3) * 32 + (lane >> 4) * 8;
      bf16x8 o;
#pragma unroll
      for (int e = 0; e < 8; ++e) o[e] = (short)f2bf(Wqkv[(size_t)(k + e) * NQKV + j]);
      *(bf16x8*)&Wqf[(size_t)gg * 8] = o;
    } else {
      int gg = g - NXG - NQG;
      int lane = gg & 63, f = (gg >> 6) & 15, kt = (gg >> 10) & 7, nt = gg >> 13;
      int j = nt * 128 + (f & 7) * 16 + (lane & 15);
      int k = kt * 64 + (f >> 3) * 32 + (lane >> 4) * 8;
      bf16x8 o;
#pragma unroll
      for (int e = 0; e < 8; ++e) o[e] = (short)f2bf(Wout[(size_t)(k + e) * 512 + j]);
      *(bf16x8*)&Wof[(size_t)gg * 8] = o;
    }
  }
}

// ---------------------------------------------------------------------------
// Pipelined GEMM (unchanged from round 6).
// ---------------------------------------------------------------------------
template<int MODE>
__global__ __launch_bounds__(256, 2) void gemm_kernel(
    const u16* __restrict__ Af, const u16* __restrict__ Bf,
    const float* __restrict__ bias, int nb,
    u16* __restrict__ Qb, u16* __restrict__ Kf, u16* __restrict__ Vf,
    float* __restrict__ Cout)
{
  __shared__ u16 ldsA[2][16 * 512];
  __shared__ u16 ldsB[2][16 * 512];

  const int t  = threadIdx.x;
  const int l  = t & 63;
  const int w  = t >> 6;
  const int lr = l >> 4, lc = l & 15;

  const int nwg = gridDim.x;
  const int qq = nwg >> 3, rr8 = nwg & 7;
  const int xcd = blockIdx.x & 7, off = blockIdx.x >> 3;
  const int wgid = (xcd < rr8 ? xcd * (qq + 1) : rr8 * (qq + 1) + (xcd - rr8) * qq) + off;
  const int m0 = (wgid / nb) * 128;
  const int n0 = (wgid % nb) * 128;

  const u16* pA = Af + ((size_t)(m0 >> 7) * 128 + w) * 512 + l * 8;
  const u16* pB = Bf + ((size_t)(n0 >> 7) * 128 + w) * 512 + l * 8;

  f32x4 acc[4][4] = {};

#pragma unroll
  for (int c = 0; c < 4; ++c) {
    async_copy16(&ldsA[0][(c * 4 + w) * 512], pA + c * 2048);
    async_copy16(&ldsB[0][(c * 4 + w) * 512], pB + c * 2048);
  }
  __syncthreads();

  for (int kt = 0; kt < 8; ++kt) {
    const int cur = kt & 1;
    if (kt < 7) {
      const u16* qA = pA + (kt + 1) * 8192;
      const u16* qB = pB + (kt + 1) * 8192;
#pragma unroll
      for (int c = 0; c < 4; ++c) {
        async_copy16(&ldsA[cur ^ 1][(c * 4 + w) * 512], qA + c * 2048);
        async_copy16(&ldsB[cur ^ 1][(c * 4 + w) * 512], qB + c * 2048);
      }
    }
#pragma unroll
    for (int kk = 0; kk < 2; ++kk) {
      bf16x8 af[4], bfr[4];
#pragma unroll
      for (int m = 0; m < 4; ++m)
        af[m] = *(bf16x8*)&ldsA[cur][((kk * 8 + (w >> 1) * 4 + m) * 64 + l) * 8];
#pragma unroll
      for (int n = 0; n < 4; ++n)
        bfr[n] = *(bf16x8*)&ldsB[cur][((kk * 8 + (w & 1) * 4 + n) * 64 + l) * 8];
      __builtin_amdgcn_s_setprio(1);
#pragma unroll
      for (int m = 0; m < 4; ++m)
#pragma unroll
        for (int n = 0; n < 4; ++n)
          acc[m][n] = __builtin_amdgcn_mfma_f32_16x16x32_bf16(af[m], bfr[n], acc[m][n], 0, 0, 0);
      __builtin_amdgcn_s_setprio(0);
    }
    __syncthreads();
  }

  int jv[4]; float bj[4];
#pragma unroll
  for (int n = 0; n < 4; ++n) { jv[n] = n0 + (w & 1) * 64 + n * 16 + lc; bj[n] = bias[jv[n]]; }

#pragma unroll
  for (int m = 0; m < 4; ++m) {
#pragma unroll
    for (int r = 0; r < 4; ++r) {
      int i = m0 + (w >> 1) * 64 + m * 16 + lr * 4 + r;
      if (i >= MTOK) continue;
      if (MODE == 0) {
        int b = i / S_, s = i - b * S_;
        int stK  = s >> 5;
        int nfs  = (s >> 4) & 1;
        int lisK = s & 15;
        int lvhi = (s >> 3) & 3;
        int es   = s & 7;
#pragma unroll
        for (int n = 0; n < 4; ++n) {
          int j = jv[n];
          int which = j >> 9, h = (j >> 8) & 1, d = j & 255;
          int bh = b * H_ + h;
          u16 v = f2bf(acc[m][n][r] + bj[n]);
          if (which == 0) {
            Qb[((size_t)(bh * SPAD + s)) * HD_ + d] = v;
          } else if (which == 1) {
            Kf[(((size_t)(bh * NKT + stK)) * 16 + (d >> 5) * 2 + nfs) * 512 +
               (((d >> 3) & 3) * 16 + lisK) * 8 + (d & 7)] = v;
          } else {
            Vf[(((size_t)(bh * NKT + stK)) * 16 + (d >> 4)) * 512 +
               (lvhi * 16 + (d & 15)) * 8 + es] = v;
          }
        }
      } else {
#pragma unroll
        for (int n = 0; n < 4; ++n)
          Cout[(size_t)i * D_ + jv[n]] = acc[m][n][r] + bj[n];
      }
    }
  }
}

// ---------------------------------------------------------------------------
// Kernel 3: causal flash attention v6 — SWAPPED-OPERAND softmax (T12).
// QK^T computed as mfma(K, Q) -> each lane owns ONE q-row (col=lane&15):
// row-max = in-lane 8-val tree + 2 shfls (was 16); mrow/lsum are per-lane
// scalars; rescale is lane-uniform. PV swapped too: mfma(Vfrag, Pfrag) ->
// oacc col=q matches softmax lane-space (Vf bytes unchanged: rows=d over kv
// serve as A-operand as-is). Barrier moved AFTER softmax / BEFORE PV: PV +
// next QK issue back-to-back; barrier fence pins V loads early (T14).
// Structure otherwise = round 6/8: 4 waves x 16 q, grid 608, KVBLK=32,
// K LDS-dbuf, V direct-to-registers.
// ---------------------------------------------------------------------------
__global__ __launch_bounds__(256, 2) void attn_kernel(
    const u16* __restrict__ Qb, const u16* __restrict__ Kf,
    const u16* __restrict__ Vf, u16* __restrict__ Obf)
{
  __shared__ u16 ldsK[2][16 * 512];     // 2 x 16 KiB, frag = kb*2+nf
  __shared__ u16 ldsP[4][16 * 36];      // per-wave P [16 q][32 kv], pad 36

  const int id   = blockIdx.x;          // 0..607
  const int xcd  = id & 7;
  const int slot = id >> 3;             // 0..75
  const int bh   = xcd + 8 * (slot / 19);
  const int qt   = 18 - (slot % 19);    // long blocks first
  const int q0   = qt * 64;
  const int nkv  = 2 * qt + 2;          // kv tiles of 32
  const int t  = threadIdx.x, l = t & 63, w = t >> 6;
  const int lr = l >> 4, lc = l & 15;
  const int wq0 = q0 + w * 16;          // wave's first q row
  const int qrow_l = wq0 + lc;          // THIS lane's q row (swapped space)

  // Q fragments (B-operand rows=q over d): 8 d-blocks of 32 — bytes unchanged
  bf16x8 qf[8];
  const u16* qbase = Qb + (size_t)(bh * SPAD + qrow_l) * HD_ + lr * 8;
#pragma unroll
  for (int kb = 0; kb < 8; ++kb)
    qf[kb] = *(const bf16x8*)(qbase + kb * 32);

  f32x4 oacc[16] = {};                  // [d-block]; col=q=lc, reg=d-sub
  float mrow = -1e30f, lsum = 0.f;      // per-lane scalars (q = lc)

  // prologue: stage K tile 0 into buf 0
  {
    const u16* kb_ = Kf + (((size_t)(bh * NKT)) * 16 + w) * 512 + l * 8;
#pragma unroll
    for (int c = 0; c < 4; ++c)
      async_copy16(&ldsK[0][(c * 4 + w) * 512], kb_ + c * 2048);
  }
  __syncthreads();

  for (int kt = 0; kt < nkv; ++kt) {
    const int cur = kt & 1;

    // (1) V-frag loads for CURRENT tile (A-operand rows=d over kv; bytes
    // unchanged) — issued first; the pre-PV barrier fences them early.
    bf16x8 vfr[16];
    {
      const u16* vb_ = Vf + (((size_t)(bh * NKT + kt)) * 16) * 512 + l * 8;
#pragma unroll
      for (int nf = 0; nf < 16; ++nf)
        vfr[nf] = *(const bf16x8*)(vb_ + nf * 512);
    }

    // (2) next K tile's stages (in flight across QK + softmax)
    if (kt + 1 < nkv) {
      const u16* kb_ = Kf + (((size_t)(bh * NKT + kt + 1)) * 16 + w) * 512 + l * 8;
#pragma unroll
      for (int c = 0; c < 4; ++c)
        async_copy16(&ldsK[cur ^ 1][(c * 4 + w) * 512], kb_ + c * 2048);
    }

    // (3) S^T = K @ Q^T : A=kf (rows=kv), B=qf (rows=q) -> col=q, row=kv
    f32x4 sacc[2] = {};
    __builtin_amdgcn_s_setprio(1);
#pragma unroll
    for (int kb = 0; kb < 8; ++kb) {
#pragma unroll
      for (int nf = 0; nf < 2; ++nf) {
        bf16x8 kf = *(bf16x8*)&ldsK[cur][((kb * 2 + nf) * 64 + l) * 8];
        sacc[nf] = __builtin_amdgcn_mfma_f32_16x16x32_bf16(kf, qf[kb], sacc[nf], 0, 0, 0);
      }
    }
    __builtin_amdgcn_s_setprio(0);

    // (4) mask + scale; per-lane row-max (lane = one q-row)
    const int kv0 = kt * 32;
    float sv[2][4];
    float pm = -1e30f;
    if (kv0 + 31 <= wq0) {              // interior: kv_max <= wq0 <= qrow_l, < S_
#pragma unroll
      for (int nf = 0; nf < 2; ++nf)
#pragma unroll
        for (int r = 0; r < 4; ++r) {
          float v = sacc[nf][r] * 0.0625f;
          sv[nf][r] = v;
          pm = fmaxf(pm, v);
        }
    } else {
#pragma unroll
      for (int nf = 0; nf < 2; ++nf)
#pragma unroll
        for (int r = 0; r < 4; ++r) {
          int kv = kv0 + nf * 16 + lr * 4 + r;
          float v = ((kv <= qrow_l) && (kv < S_)) ? sacc[nf][r] * 0.0625f : -1e30f;
          sv[nf][r] = v;
          pm = fmaxf(pm, v);
        }
    }
    pm = fmaxf(pm, __shfl_xor(pm, 16));
    pm = fmaxf(pm, __shfl_xor(pm, 32));

    // defer-max (T13): per-lane scalar vote
    bool skip = (pm <= mrow + 8.0f);
    if (!__all(skip)) {
      float mn = fmaxf(mrow, pm);
      float sc = exp2f((mrow - mn) * LOG2E);
      mrow = mn;
      lsum *= sc;
#pragma unroll
      for (int nf = 0; nf < 16; ++nf)
#pragma unroll
        for (int r = 0; r < 4; ++r) oacc[nf][r] *= sc;
    }

    // exp + P-write (packed b64: 4 consecutive kv per store)
#pragma unroll
    for (int nf = 0; nf < 2; ++nf) {
      float p0 = exp2f((sv[nf][0] - mrow) * LOG2E);
      float p1 = exp2f((sv[nf][1] - mrow) * LOG2E);
      float p2 = exp2f((sv[nf][2] - mrow) * LOG2E);
      float p3 = exp2f((sv[nf][3] - mrow) * LOG2E);
      lsum += (p0 + p1) + (p2 + p3);
      uint64_t pk = (uint64_t)f2bf(p0) | ((uint64_t)f2bf(p1) << 16) |
                    ((uint64_t)f2bf(p2) << 32) | ((uint64_t)f2bf(p3) << 48);
      *(uint64_t*)&ldsP[w][lc * 36 + nf * 16 + lr * 4] = pk;
    }

    __syncthreads();  // drains vmcnt (V(kt) + K(kt+1)) + lgkm; gates buf swap

    // (5) O^T += V^T @ P^T : A=vfr (rows=d), B=pf (rows=q) -> col=q, row=d
    bf16x8 pf = *(bf16x8*)&ldsP[w][lc * 36 + lr * 8];
    __builtin_amdgcn_s_setprio(1);
#pragma unroll
    for (int nf = 0; nf < 16; ++nf)
      oacc[nf] = __builtin_amdgcn_mfma_f32_16x16x32_bf16(vfr[nf], pf, oacc[nf], 0, 0, 0);
    __builtin_amdgcn_s_setprio(0);
    // no barrier here: next iter's QK reads ldsK[cur^1] (landed; gated above),
    // and stages into ldsK[cur] happen after ALL waves passed this iter's
    // barrier having finished their ldsK[cur] reads in step (3).
  }

  // finalize: lane-local sum, reduce over the 4 kv-quarter lanes
  float s = lsum;
  s += __shfl_xor(s, 16);
  s += __shfl_xor(s, 32);
  float inv = 1.0f / s;

  const int b = bh >> 1, h = bh & 1;
  if (qrow_l < S_) {
    int i = b * S_ + qrow_l;
    int it = i >> 7, mf = (i >> 4) & 7, li = i & 15;
#pragma unroll
    for (int nf = 0; nf < 16; ++nf) {
#pragma unroll
      for (int r = 0; r < 4; ++r) {
        int j = h * HD_ + nf * 16 + lr * 4 + r;
        size_t addr = (((size_t)(it * 8 + (j >> 6))) * 16 + ((j >> 5) & 1) * 8 + mf) * 512 +
                      (((j >> 3) & 3) * 16 + li) * 8 + (j & 7);
        Obf[addr] = f2bf(oacc[nf][r] * inv);
      }
    }
  }
}

// ---------------------------------------------------------------------------
extern "C" void kernel_launch(void* const* d_in, const int* in_sizes, int n_in,
                              void* d_out, int out_size, void* d_ws, size_t ws_size,
                              hipStream_t stream) {
  const float* X    = (const float*)d_in[0];
  const float* Wqkv = (const float*)d_in[1];
  const float* bqkv = (const float*)d_in[2];
  const float* Wout = (const float*)d_in[3];
  const float* bout = (const float*)d_in[4];
  float* out = (float*)d_out;

  char* ws = (char*)d_ws;
  u16* Xf  = (u16*)ws;  ws += (size_t)MPAD * D_ * 2;
  u16* Wqf = (u16*)ws;  ws += (size_t)NQKV * D_ * 2;
  u16* Wof = (u16*)ws;  ws += (size_t)D_ * D_ * 2;
  u16* Qb  = (u16*)ws;  ws += (size_t)B_ * H_ * SPAD * HD_ * 2;
  u16* Kf  = (u16*)ws;  ws += (size_t)B_ * H_ * SPAD * HD_ * 2;
  u16* Vf  = (u16*)ws;  ws += (size_t)B_ * H_ * SPAD * HD_ * 2;
  u16* Obf = (u16*)ws;  ws += (size_t)MPAD * D_ * 2;
  // total ~101 MB

  convert_kernel<<<2048, 256, 0, stream>>>(X, Wqkv, Wout, Xf, Wqf, Wof);
  gemm_kernel<0><<<1800, 256, 0, stream>>>(Xf, Wqf, bqkv, 12, Qb, Kf, Vf, nullptr);
  attn_kernel<<<608, 256, 0, stream>>>(Qb, Kf, Vf, Obf);
  gemm_kernel<1><<<600, 256, 0, stream>>>(Obf, Wof, bout, 4, nullptr, nullptr, nullptr, out);
}

// Round 10
// 152.974 us; speedup vs baseline: 1.4797x; 1.0847x over previous
//
#include <hip/hip_runtime.h>
#include <stdint.h>

#define D_    512
#define H_    2
#define HD_   256
#define B_    16
#define S_    1194
#define MTOK  19104          // B_*S_
#define MPAD  19200          // 150*128
#define SPAD  1216           // 19*64 = 38*32
#define NQKV  1536
#define NKT   38             // kv tiles of 32 (attn)
#define LOG2E 1.44269504088896340736f

typedef unsigned short u16;
typedef __attribute__((ext_vector_type(8))) short bf16x8;   // 8 bf16 = 4 VGPR
typedef __attribute__((ext_vector_type(4))) float f32x4;

__device__ inline u16 f2bf(float x) {
  union { float f; unsigned u; } c; c.f = x;
  unsigned r = c.u + 0x7fffu + ((c.u >> 16) & 1u);  // RNE
  return (u16)(r >> 16);
}

// async global->LDS, 16B per lane. LDS dest is wave-uniform base (HW adds
// lane*16); global src per-lane, CONTIGUOUS: 1 instr = 1KB sequential.
__device__ inline void async_copy16(void* lds, const void* g) {
  __builtin_amdgcn_global_load_lds(
      (__attribute__((address_space(1))) void*)(g),
      (__attribute__((address_space(3))) void*)(lds),
      16, 0, 0);
}

// ---------------------------------------------------------------------------
// Kernel 1 (unchanged): X/W -> frag-major bf16.
// ---------------------------------------------------------------------------
__global__ void convert_kernel(const float* __restrict__ X,
                               const float* __restrict__ Wqkv,
                               const float* __restrict__ Wout,
                               u16* __restrict__ Xf,
                               u16* __restrict__ Wqf,
                               u16* __restrict__ Wof) {
  const int NXG = MPAD * 64;
  const int NQG = 12 * 8 * 16 * 64;
  const int NOG = 4 * 8 * 16 * 64;
  const int TOT = NXG + NQG + NOG;
  int stride = gridDim.x * blockDim.x;
  for (int g = blockIdx.x * blockDim.x + threadIdx.x; g < TOT; g += stride) {
    if (g < NXG) {
      int lane = g & 63, f = (g >> 6) & 15, kt = (g >> 10) & 7, mt = g >> 13;
      int i = mt * 128 + (f & 7) * 16 + (lane & 15);
      int k = kt * 64 + (f >> 3) * 32 + (lane >> 4) * 8;
      bf16x8 o;
      if (i < MTOK) {
        f32x4 v0 = *(const f32x4*)&X[(size_t)i * 512 + k];
        f32x4 v1 = *(const f32x4*)&X[(size_t)i * 512 + k + 4];
#pragma unroll
        for (int e = 0; e < 4; ++e) { o[e] = (short)f2bf(v0[e]); o[4 + e] = (short)f2bf(v1[e]); }
      } else {
#pragma unroll
        for (int e = 0; e < 8; ++e) o[e] = 0;
      }
      *(bf16x8*)&Xf[(size_t)g * 8] = o;
    } else if (g < NXG + NQG) {
      int gg = g - NXG;
      int lane = gg & 63, f = (gg >> 6) & 15, kt = (gg >> 10) & 7, nt = gg >> 13;
      int j = nt * 128 + (f & 7) * 16 + (lane & 15);
      int k = kt * 64 + (f >> 3) * 32 + (lane >> 4) * 8;
      bf16x8 o;
#pragma unroll
      for (int e = 0; e < 8; ++e) o[e] = (short)f2bf(Wqkv[(size_t)(k + e) * NQKV + j]);
      *(bf16x8*)&Wqf[(size_t)gg * 8] = o;
    } else {
      int gg = g - NXG - NQG;
      int lane = gg & 63, f = (gg >> 6) & 15, kt = (gg >> 10) & 7, nt = gg >> 13;
      int j = nt * 128 + (f & 7) * 16 + (lane & 15);
      int k = kt * 64 + (f >> 3) * 32 + (lane >> 4) * 8;
      bf16x8 o;
#pragma unroll
      for (int e = 0; e < 8; ++e) o[e] = (short)f2bf(Wout[(size_t)(k + e) * 512 + j]);
      *(bf16x8*)&Wof[(size_t)gg * 8] = o;
    }
  }
}

// ---------------------------------------------------------------------------
// GEMM v2: m97 single-buffer schedule — {barrier, stage(kt), barrier(drain),
// compute(kt)} with 32 KB LDS. VGPR 88 -> wave-limited 4 blocks/CU; the
// barrier-drain stall of one block is covered by the other 3 (m114 implicit
// overlap — the mechanism behind m97's 874 TF). Our "dbuf" variant drained
// vmcnt(0) right after issuing next-tile loads: full latency exposed/step.
// ---------------------------------------------------------------------------
template<int MODE>
__global__ __launch_bounds__(256, 2) void gemm_kernel(
    const u16* __restrict__ Af, const u16* __restrict__ Bf,
    const float* __restrict__ bias, int nb,
    u16* __restrict__ Qb, u16* __restrict__ Kf, u16* __restrict__ Vf,
    float* __restrict__ Cout)
{
  __shared__ u16 ldsA[16 * 512];       // 16 KiB (single buffer)
  __shared__ u16 ldsB[16 * 512];

  const int t  = threadIdx.x;
  const int l  = t & 63;
  const int w  = t >> 6;
  const int lr = l >> 4, lc = l & 15;

  const int nwg = gridDim.x;
  const int qq = nwg >> 3, rr8 = nwg & 7;
  const int xcd = blockIdx.x & 7, off = blockIdx.x >> 3;
  const int wgid = (xcd < rr8 ? xcd * (qq + 1) : rr8 * (qq + 1) + (xcd - rr8) * qq) + off;
  const int m0 = (wgid / nb) * 128;
  const int n0 = (wgid % nb) * 128;

  const u16* pA = Af + ((size_t)(m0 >> 7) * 128 + w) * 512 + l * 8;
  const u16* pB = Bf + ((size_t)(n0 >> 7) * 128 + w) * 512 + l * 8;

  f32x4 acc[4][4] = {};

  for (int kt = 0; kt < 8; ++kt) {
    __syncthreads();                   // prev compute done: buffer reusable
    const u16* qA = pA + kt * 8192;
    const u16* qB = pB + kt * 8192;
#pragma unroll
    for (int c = 0; c < 4; ++c) {
      async_copy16(&ldsA[(c * 4 + w) * 512], qA + c * 2048);
      async_copy16(&ldsB[(c * 4 + w) * 512], qB + c * 2048);
    }
    __syncthreads();                   // stage landed (vmcnt drain)
#pragma unroll
    for (int kk = 0; kk < 2; ++kk) {
      bf16x8 af[4], bfr[4];
#pragma unroll
      for (int m = 0; m < 4; ++m)
        af[m] = *(bf16x8*)&ldsA[((kk * 8 + (w >> 1) * 4 + m) * 64 + l) * 8];
#pragma unroll
      for (int n = 0; n < 4; ++n)
        bfr[n] = *(bf16x8*)&ldsB[((kk * 8 + (w & 1) * 4 + n) * 64 + l) * 8];
      __builtin_amdgcn_s_setprio(1);
#pragma unroll
      for (int m = 0; m < 4; ++m)
#pragma unroll
        for (int n = 0; n < 4; ++n)
          acc[m][n] = __builtin_amdgcn_mfma_f32_16x16x32_bf16(af[m], bfr[n], acc[m][n], 0, 0, 0);
      __builtin_amdgcn_s_setprio(0);
    }
  }

  int jv[4]; float bj[4];
#pragma unroll
  for (int n = 0; n < 4; ++n) { jv[n] = n0 + (w & 1) * 64 + n * 16 + lc; bj[n] = bias[jv[n]]; }

#pragma unroll
  for (int m = 0; m < 4; ++m) {
#pragma unroll
    for (int r = 0; r < 4; ++r) {
      int i = m0 + (w >> 1) * 64 + m * 16 + lr * 4 + r;
      if (i >= MTOK) continue;
      if (MODE == 0) {
        int b = i / S_, s = i - b * S_;
        int stK  = s >> 5;
        int nfs  = (s >> 4) & 1;
        int lisK = s & 15;
        int lvhi = (s >> 3) & 3;
        int es   = s & 7;
#pragma unroll
        for (int n = 0; n < 4; ++n) {
          int j = jv[n];
          int which = j >> 9, h = (j >> 8) & 1, d = j & 255;
          int bh = b * H_ + h;
          u16 v = f2bf(acc[m][n][r] + bj[n]);
          if (which == 0) {
            Qb[((size_t)(bh * SPAD + s)) * HD_ + d] = v;
          } else if (which == 1) {
            Kf[(((size_t)(bh * NKT + stK)) * 16 + (d >> 5) * 2 + nfs) * 512 +
               (((d >> 3) & 3) * 16 + lisK) * 8 + (d & 7)] = v;
          } else {
            Vf[(((size_t)(bh * NKT + stK)) * 16 + (d >> 4)) * 512 +
               (lvhi * 16 + (d & 15)) * 8 + es] = v;
          }
        }
      } else {
#pragma unroll
        for (int n = 0; n < 4; ++n)
          Cout[(size_t)i * D_ + jv[n]] = acc[m][n][r] + bj[n];
      }
    }
  }
}

// ---------------------------------------------------------------------------
// Kernel 3: causal flash attention v6 (unchanged from round 9).
// ---------------------------------------------------------------------------
__global__ __launch_bounds__(256, 2) void attn_kernel(
    const u16* __restrict__ Qb, const u16* __restrict__ Kf,
    const u16* __restrict__ Vf, u16* __restrict__ Obf)
{
  __shared__ u16 ldsK[2][16 * 512];     // 2 x 16 KiB, frag = kb*2+nf
  __shared__ u16 ldsP[4][16 * 36];      // per-wave P [16 q][32 kv], pad 36

  const int id   = blockIdx.x;          // 0..607
  const int xcd  = id & 7;
  const int slot = id >> 3;             // 0..75
  const int bh   = xcd + 8 * (slot / 19);
  const int qt   = 18 - (slot % 19);    // long blocks first
  const int q0   = qt * 64;
  const int nkv  = 2 * qt + 2;          // kv tiles of 32
  const int t  = threadIdx.x, l = t & 63, w = t >> 6;
  const int lr = l >> 4, lc = l & 15;
  const int wq0 = q0 + w * 16;          // wave's first q row
  const int qrow_l = wq0 + lc;          // THIS lane's q row (swapped space)

  // Q fragments (B-operand rows=q over d): 8 d-blocks of 32
  bf16x8 qf[8];
  const u16* qbase = Qb + (size_t)(bh * SPAD + qrow_l) * HD_ + lr * 8;
#pragma unroll
  for (int kb = 0; kb < 8; ++kb)
    qf[kb] = *(const bf16x8*)(qbase + kb * 32);

  f32x4 oacc[16] = {};                  // [d-block]; col=q=lc, reg=d-sub
  float mrow = -1e30f, lsum = 0.f;      // per-lane scalars (q = lc)

  // prologue: stage K tile 0 into buf 0
  {
    const u16* kb_ = Kf + (((size_t)(bh * NKT)) * 16 + w) * 512 + l * 8;
#pragma unroll
    for (int c = 0; c < 4; ++c)
      async_copy16(&ldsK[0][(c * 4 + w) * 512], kb_ + c * 2048);
  }
  __syncthreads();

  for (int kt = 0; kt < nkv; ++kt) {
    const int cur = kt & 1;

    // (1) V-frag loads for CURRENT tile — issued first
    bf16x8 vfr[16];
    {
      const u16* vb_ = Vf + (((size_t)(bh * NKT + kt)) * 16) * 512 + l * 8;
#pragma unroll
      for (int nf = 0; nf < 16; ++nf)
        vfr[nf] = *(const bf16x8*)(vb_ + nf * 512);
    }

    // (2) next K tile's stages (in flight across QK + softmax)
    if (kt + 1 < nkv) {
      const u16* kb_ = Kf + (((size_t)(bh * NKT + kt + 1)) * 16 + w) * 512 + l * 8;
#pragma unroll
      for (int c = 0; c < 4; ++c)
        async_copy16(&ldsK[cur ^ 1][(c * 4 + w) * 512], kb_ + c * 2048);
    }

    // (3) S^T = K @ Q^T : A=kf (rows=kv), B=qf (rows=q) -> col=q, row=kv
    f32x4 sacc[2] = {};
    __builtin_amdgcn_s_setprio(1);
#pragma unroll
    for (int kb = 0; kb < 8; ++kb) {
#pragma unroll
      for (int nf = 0; nf < 2; ++nf) {
        bf16x8 kf = *(bf16x8*)&ldsK[cur][((kb * 2 + nf) * 64 + l) * 8];
        sacc[nf] = __builtin_amdgcn_mfma_f32_16x16x32_bf16(kf, qf[kb], sacc[nf], 0, 0, 0);
      }
    }
    __builtin_amdgcn_s_setprio(0);

    // (4) mask + scale; per-lane row-max (lane = one q-row)
    const int kv0 = kt * 32;
    float sv[2][4];
    float pm = -1e30f;
    if (kv0 + 31 <= wq0) {              // interior
#pragma unroll
      for (int nf = 0; nf < 2; ++nf)
#pragma unroll
        for (int r = 0; r < 4; ++r) {
          float v = sacc[nf][r] * 0.0625f;
          sv[nf][r] = v;
          pm = fmaxf(pm, v);
        }
    } else {
#pragma unroll
      for (int nf = 0; nf < 2; ++nf)
#pragma unroll
        for (int r = 0; r < 4; ++r) {
          int kv = kv0 + nf * 16 + lr * 4 + r;
          float v = ((kv <= qrow_l) && (kv < S_)) ? sacc[nf][r] * 0.0625f : -1e30f;
          sv[nf][r] = v;
          pm = fmaxf(pm, v);
        }
    }
    pm = fmaxf(pm, __shfl_xor(pm, 16));
    pm = fmaxf(pm, __shfl_xor(pm, 32));

    // defer-max (T13)
    bool skip = (pm <= mrow + 8.0f);
    if (!__all(skip)) {
      float mn = fmaxf(mrow, pm);
      float sc = exp2f((mrow - mn) * LOG2E);
      mrow = mn;
      lsum *= sc;
#pragma unroll
      for (int nf = 0; nf < 16; ++nf)
#pragma unroll
        for (int r = 0; r < 4; ++r) oacc[nf][r] *= sc;
    }

    // exp + P-write (packed b64)
#pragma unroll
    for (int nf = 0; nf < 2; ++nf) {
      float p0 = exp2f((sv[nf][0] - mrow) * LOG2E);
      float p1 = exp2f((sv[nf][1] - mrow) * LOG2E);
      float p2 = exp2f((sv[nf][2] - mrow) * LOG2E);
      float p3 = exp2f((sv[nf][3] - mrow) * LOG2E);
      lsum += (p0 + p1) + (p2 + p3);
      uint64_t pk = (uint64_t)f2bf(p0) | ((uint64_t)f2bf(p1) << 16) |
                    ((uint64_t)f2bf(p2) << 32) | ((uint64_t)f2bf(p3) << 48);
      *(uint64_t*)&ldsP[w][lc * 36 + nf * 16 + lr * 4] = pk;
    }

    __syncthreads();  // drains vmcnt (V(kt) + K(kt+1)) + lgkm; gates buf swap

    // (5) O^T += V^T @ P^T : A=vfr (rows=d), B=pf (rows=q) -> col=q, row=d
    bf16x8 pf = *(bf16x8*)&ldsP[w][lc * 36 + lr * 8];
    __builtin_amdgcn_s_setprio(1);
#pragma unroll
    for (int nf = 0; nf < 16; ++nf)
      oacc[nf] = __builtin_amdgcn_mfma_f32_16x16x32_bf16(vfr[nf], pf, oacc[nf], 0, 0, 0);
    __builtin_amdgcn_s_setprio(0);
  }

  // finalize
  float s = lsum;
  s += __shfl_xor(s, 16);
  s += __shfl_xor(s, 32);
  float inv = 1.0f / s;

  const int b = bh >> 1, h = bh & 1;
  if (qrow_l < S_) {
    int i = b * S_ + qrow_l;
    int it = i >> 7, mf = (i >> 4) & 7, li = i & 15;
#pragma unroll
    for (int nf = 0; nf < 16; ++nf) {
#pragma unroll
      for (int r = 0; r < 4; ++r) {
        int j = h * HD_ + nf * 16 + lr * 4 + r;
        size_t addr = (((size_t)(it * 8 + (j >> 6))) * 16 + ((j >> 5) & 1) * 8 + mf) * 512 +
                      (((j >> 3) & 3) * 16 + li) * 8 + (j & 7);
        Obf[addr] = f2bf(oacc[nf][r] * inv);
      }
    }
  }
}

// ---------------------------------------------------------------------------
extern "C" void kernel_launch(void* const* d_in, const int* in_sizes, int n_in,
                              void* d_out, int out_size, void* d_ws, size_t ws_size,
                              hipStream_t stream) {
  const float* X    = (const float*)d_in[0];
  const float* Wqkv = (const float*)d_in[1];
  const float* bqkv = (const float*)d_in[2];
  const float* Wout = (const float*)d_in[3];
  const float* bout = (const float*)d_in[4];
  float* out = (float*)d_out;

  char* ws = (char*)d_ws;
  u16* Xf  = (u16*)ws;  ws += (size_t)MPAD * D_ * 2;
  u16* Wqf = (u16*)ws;  ws += (size_t)NQKV * D_ * 2;
  u16* Wof = (u16*)ws;  ws += (size_t)D_ * D_ * 2;
  u16* Qb  = (u16*)ws;  ws += (size_t)B_ * H_ * SPAD * HD_ * 2;
  u16* Kf  = (u16*)ws;  ws += (size_t)B_ * H_ * SPAD * HD_ * 2;
  u16* Vf  = (u16*)ws;  ws += (size_t)B_ * H_ * SPAD * HD_ * 2;
  u16* Obf = (u16*)ws;  ws += (size_t)MPAD * D_ * 2;
  // total ~101 MB

  convert_kernel<<<2048, 256, 0, stream>>>(X, Wqkv, Wout, Xf, Wqf, Wof);
  gemm_kernel<0><<<1800, 256, 0, stream>>>(Xf, Wqf, bqkv, 12, Qb, Kf, Vf, nullptr);
  attn_kernel<<<608, 256, 0, stream>>>(Qb, Kf, Vf, Obf);
  gemm_kernel<1><<<600, 256, 0, stream>>>(Obf, Wof, bout, 4, nullptr, nullptr, nullptr, out);
}